// Round 4
// baseline (469.264 us; speedup 1.0000x reference)
//
#include <hip/hip_runtime.h>
#include <stdint.h>

// ---------------------------------------------------------------------------
// MambaLikeBlock on MI355X (gfx950)
// R10: m201-style phase discipline. Each K-tile (BK=32) = 2 phases of 16
//     MFMAs, each phase: {ds_read frags -> 2x global_load_lds -> [counted
//     vmcnt once per tile] -> s_barrier -> lgkmcnt(0) -> sched_barrier ->
//     setprio(1) -> 16 MFMA -> setprio(0) -> s_barrier}. The barrier
//     BETWEEN read-issue and lgkm-wait lets other waves' MFMA window cover
//     ds_read latency; double-barrier lockstep keeps all 8 waves' MFMA
//     clusters coincident (m196/m201 mechanism). R9 (1 barrier/iter,
//     lgkm-wait right after issue) measured identical to R8 -> intra-phase
//     reordering alone is not the lever; this is the verified structure.
// ---------------------------------------------------------------------------

#define L_SEQ 32768
#define CDIM 512
#define LN_EPS 1e-5f
#define CHUNK 64
#define NCHUNK (L_SEQ / CHUNK) // 512

typedef __attribute__((ext_vector_type(8))) short short8;
typedef __attribute__((ext_vector_type(4))) float floatx4;
typedef __attribute__((ext_vector_type(4))) int intx4;

__device__ inline unsigned short f2bf(float f) {
  union { float f; unsigned int u; } v; v.f = f;
  unsigned int r = v.u + 0x7fffu + ((v.u >> 16) & 1u);
  return (unsigned short)(r >> 16);
}
__device__ inline float bf2f(unsigned short h) {
  union { float f; unsigned int u; } v; v.u = ((unsigned int)h) << 16;
  return v.f;
}
__device__ inline float sigmoidf_(float x) { return 1.0f / (1.0f + __expf(-x)); }
__device__ __forceinline__ short8 asS8(intx4 v) {
  union { intx4 i; short8 s; } u; u.i = v; return u.s;
}

// global -> LDS direct copy, 16B per lane.
__device__ __forceinline__ void gll16(const void* g, void* l) {
  __builtin_amdgcn_global_load_lds(
      (__attribute__((address_space(1))) void*)g,
      (__attribute__((address_space(3))) void*)l, 16, 0, 0);
}

// ---------------- LayerNorm: one wave per row (C=512 = 64 lanes x 8) -------
__global__ __launch_bounds__(256) void ln_kernel(const float* __restrict__ x,
    const float* __restrict__ w, const float* __restrict__ b,
    unsigned short* __restrict__ out) {
  int row = blockIdx.x * 4 + (threadIdx.x >> 6);
  int lane = threadIdx.x & 63;
  const float4* xr = (const float4*)(x + (size_t)row * CDIM);
  float4 v0 = xr[lane * 2];
  float4 v1 = xr[lane * 2 + 1];
  float s = v0.x + v0.y + v0.z + v0.w + v1.x + v1.y + v1.z + v1.w;
  float s2 = v0.x * v0.x + v0.y * v0.y + v0.z * v0.z + v0.w * v0.w +
             v1.x * v1.x + v1.y * v1.y + v1.z * v1.z + v1.w * v1.w;
  for (int m = 32; m > 0; m >>= 1) {
    s += __shfl_xor(s, m, 64);
    s2 += __shfl_xor(s2, m, 64);
  }
  float mean = s * (1.0f / CDIM);
  float var = s2 * (1.0f / CDIM) - mean * mean;
  float rs = rsqrtf(var + LN_EPS);
  const float4* wr = (const float4*)w;
  const float4* br = (const float4*)b;
  float4 w0 = wr[lane * 2], w1 = wr[lane * 2 + 1];
  float4 b0 = br[lane * 2], b1 = br[lane * 2 + 1];
  unsigned int p0 = (unsigned int)f2bf((v0.x - mean) * rs * w0.x + b0.x) |
                    ((unsigned int)f2bf((v0.y - mean) * rs * w0.y + b0.y) << 16);
  unsigned int p1 = (unsigned int)f2bf((v0.z - mean) * rs * w0.z + b0.z) |
                    ((unsigned int)f2bf((v0.w - mean) * rs * w0.w + b0.w) << 16);
  unsigned int p2 = (unsigned int)f2bf((v1.x - mean) * rs * w1.x + b1.x) |
                    ((unsigned int)f2bf((v1.y - mean) * rs * w1.y + b1.y) << 16);
  unsigned int p3 = (unsigned int)f2bf((v1.z - mean) * rs * w1.z + b1.z) |
                    ((unsigned int)f2bf((v1.w - mean) * rs * w1.w + b1.w) << 16);
  uint4 pk; pk.x = p0; pk.y = p1; pk.z = p2; pk.w = p3;
  *((uint4*)(out + (size_t)row * CDIM + lane * 8)) = pk;
}

// ---------------- Combined prep: 5 weight transposes + decay (1 launch) ----
__global__ __launch_bounds__(256) void prep_all(
    const float* __restrict__ W_in, const float* __restrict__ W_gate,
    const float* __restrict__ W_out, const float* __restrict__ W_ff1,
    const float* __restrict__ W_ff2, const float* __restrict__ logit,
    unsigned short* __restrict__ Wt_ig, unsigned short* __restrict__ Wt_out,
    unsigned short* __restrict__ Wt_ff1, unsigned short* __restrict__ Wt_ff2,
    float* __restrict__ decay, float* __restrict__ decayT) {
  int b = blockIdx.x;
  if (b >= 1792) { // decay prep
    for (int c = threadIdx.x; c < CDIM; c += 256) {
      float d = sigmoidf_(logit[c]);
      decay[c] = d;
      float p = d;
      for (int i = 0; i < 6; i++) p *= p; // d^64
      decayT[c] = p;
    }
    return;
  }
  const float* W; unsigned short* Wt; int Kd, Nd, t;
  if (b < 256)       { W = W_in;   Wt = Wt_ig;             Kd = 512;  Nd = 512;  t = b; }
  else if (b < 512)  { W = W_gate; Wt = Wt_ig + 512 * 512; Kd = 512;  Nd = 512;  t = b - 256; }
  else if (b < 768)  { W = W_out;  Wt = Wt_out;            Kd = 512;  Nd = 512;  t = b - 512; }
  else if (b < 1280) { W = W_ff1;  Wt = Wt_ff1;            Kd = 512;  Nd = 1024; t = b - 768; }
  else               { W = W_ff2;  Wt = Wt_ff2;            Kd = 1024; Nd = 512;  t = b - 1280; }
  int ntx = Nd >> 5;
  int n0 = (t % ntx) * 32, k0 = (t / ntx) * 32;
  __shared__ float tile[32][33];
  int tx = threadIdx.x & 31, ty = threadIdx.x >> 5; // 32x8
  for (int r = 0; r < 32; r += 8)
    tile[ty + r][tx] = W[(size_t)(k0 + ty + r) * Nd + n0 + tx];
  __syncthreads();
  for (int r = 0; r < 32; r += 8)
    Wt[(size_t)(n0 + ty + r) * Kd + k0 + tx] = f2bf(tile[tx][ty + r]);
}

// ---------------- bf16 MFMA GEMM: C = A(MxK) * Bt(NxK)^T + epilogue --------
// 256x256 tile, 512 threads = 8 waves (2M x 4N), per-wave 128x64 output
// (8x4 16x16 frags). BK=32. LDS: 4-slot ring for A and B (128 KB total).
// K-tile = 2 phases of 16 MFMAs with double-barrier lockstep (m201).
template <int EPI>
__global__ __launch_bounds__(512, 2) void gemm256(
    const unsigned short* __restrict__ A, const unsigned short* __restrict__ Bt,
    const float* __restrict__ biasA, const float* __restrict__ biasB,
    const float* __restrict__ res, float* __restrict__ outF,
    unsigned short* __restrict__ outU, unsigned short* __restrict__ outG,
    int M, int N, int K) {
  __shared__ unsigned short smem[65536];       // 128 KB
  unsigned short* As = smem;                   // 4 slots x 8192 elems
  unsigned short* Bs = smem + 32768;           // 4 slots x 8192 elems

  // XCD-aware remap (grid sizes 256/512 are both %8==0 -> bijective)
  int nbx = gridDim.x, nby = gridDim.y;
  int bid = blockIdx.x + blockIdx.y * nbx;
  int per = (nbx * nby) >> 3;
  int w = (bid & 7) * per + (bid >> 3);
  int ni = w % nby, mi = w / nby;
  int bm = mi << 8, bn = ni << 8;

  int tid = threadIdx.x, wave = tid >> 6, lane = tid & 63;
  int wm = (wave >> 2) * 128, wn = (wave & 3) * 64;
  int quad = lane >> 4, r16 = lane & 15;

  // ---- staging addressing (same swizzle as R8/R9; measured 0 conflicts) ----
  int sr = tid >> 2;             // 0..127 (row within half-tile)
  int sc = tid & 3;              // dst chunk
  int swz = (sr >> 1) & 3;
  const unsigned short* aSrc0 = A + (size_t)(bm + sr) * K + ((sc ^ swz) * 8);
  const unsigned short* aSrc1 = aSrc0 + (size_t)128 * K;
  const unsigned short* bSrc0 = Bt + (size_t)(bn + sr) * K + ((sc ^ swz) * 8);
  const unsigned short* bSrc1 = bSrc0 + (size_t)128 * K;
  int ldsW = wave * 512;         // wave-uniform LDS base (elems)

#define STAGE4(slot, ktile) do {                                  \
    int _o = (ktile) * 32;                                        \
    unsigned short* _a = As + (slot) * 8192 + ldsW;               \
    unsigned short* _b = Bs + (slot) * 8192 + ldsW;               \
    gll16(aSrc0 + _o, _a);                                        \
    gll16(aSrc1 + _o, _a + 4096);                                 \
    gll16(bSrc0 + _o, _b);                                        \
    gll16(bSrc1 + _o, _b + 4096);                                 \
  } while (0)

  floatx4 acc[8][4];
#pragma unroll
  for (int i = 0; i < 8; i++)
#pragma unroll
    for (int j = 0; j < 4; j++) acc[i][j] = (floatx4){0.f, 0.f, 0.f, 0.f};

  // fragment read addressing (dewizzle): chunk = quad ^ ((r16>>1)&3)
  int cOff = ((quad ^ ((r16 >> 1) & 3)) & 3) * 8;
  unsigned aByte = (unsigned)(((wm + r16) * 32 + cOff) * 2);            // As elem*2
  unsigned bByte = 65536u + (unsigned)(((wn + r16) * 32 + cOff) * 2);   // Bs base

  int NK = K >> 5;  // 16 or 32; needs NK >= 4

  // asm ds_read_b128 from LDS byte offset (AS3 pointer -> 32-bit vaddr)
#define DSR(dst, byteOff) asm volatile("ds_read_b128 %0, %1"              \
    : "=v"(dst)                                                           \
    : "v"((__attribute__((address_space(3))) const void*)                 \
          ((const char*)smem + (byteOff))))

  // 16 MFMAs: m-frags MB..MB+3 (a-frags A0..A3) x all 4 b-frags
#define MFMA16(MB, A0, A1, A2, A3) do {                                   \
    __builtin_amdgcn_s_setprio(1);                                        \
    short8 _b0 = asS8(tb0), _b1 = asS8(tb1), _b2 = asS8(tb2), _b3 = asS8(tb3); \
    short8 _a0 = asS8(A0), _a1 = asS8(A1), _a2 = asS8(A2), _a3 = asS8(A3);\
    acc[(MB)  ][0] = __builtin_amdgcn_mfma_f32_16x16x32_bf16(_a0, _b0, acc[(MB)  ][0], 0, 0, 0); \
    acc[(MB)  ][1] = __builtin_amdgcn_mfma_f32_16x16x32_bf16(_a0, _b1, acc[(MB)  ][1], 0, 0, 0); \
    acc[(MB)  ][2] = __builtin_amdgcn_mfma_f32_16x16x32_bf16(_a0, _b2, acc[(MB)  ][2], 0, 0, 0); \
    acc[(MB)  ][3] = __builtin_amdgcn_mfma_f32_16x16x32_bf16(_a0, _b3, acc[(MB)  ][3], 0, 0, 0); \
    acc[(MB)+1][0] = __builtin_amdgcn_mfma_f32_16x16x32_bf16(_a1, _b0, acc[(MB)+1][0], 0, 0, 0); \
    acc[(MB)+1][1] = __builtin_amdgcn_mfma_f32_16x16x32_bf16(_a1, _b1, acc[(MB)+1][1], 0, 0, 0); \
    acc[(MB)+1][2] = __builtin_amdgcn_mfma_f32_16x16x32_bf16(_a1, _b2, acc[(MB)+1][2], 0, 0, 0); \
    acc[(MB)+1][3] = __builtin_amdgcn_mfma_f32_16x16x32_bf16(_a1, _b3, acc[(MB)+1][3], 0, 0, 0); \
    acc[(MB)+2][0] = __builtin_amdgcn_mfma_f32_16x16x32_bf16(_a2, _b0, acc[(MB)+2][0], 0, 0, 0); \
    acc[(MB)+2][1] = __builtin_amdgcn_mfma_f32_16x16x32_bf16(_a2, _b1, acc[(MB)+2][1], 0, 0, 0); \
    acc[(MB)+2][2] = __builtin_amdgcn_mfma_f32_16x16x32_bf16(_a2, _b2, acc[(MB)+2][2], 0, 0, 0); \
    acc[(MB)+2][3] = __builtin_amdgcn_mfma_f32_16x16x32_bf16(_a2, _b3, acc[(MB)+2][3], 0, 0, 0); \
    acc[(MB)+3][0] = __builtin_amdgcn_mfma_f32_16x16x32_bf16(_a3, _b0, acc[(MB)+3][0], 0, 0, 0); \
    acc[(MB)+3][1] = __builtin_amdgcn_mfma_f32_16x16x32_bf16(_a3, _b1, acc[(MB)+3][1], 0, 0, 0); \
    acc[(MB)+3][2] = __builtin_amdgcn_mfma_f32_16x16x32_bf16(_a3, _b2, acc[(MB)+3][2], 0, 0, 0); \
    acc[(MB)+3][3] = __builtin_amdgcn_mfma_f32_16x16x32_bf16(_a3, _b3, acc[(MB)+3][3], 0, 0, 0); \
    __builtin_amdgcn_s_setprio(0);                                        \
  } while (0)

  // prologue: stage tiles 0,1,2; wait tile0 (allow 8 = tiles 1,2 in flight)
  STAGE4(0, 0); STAGE4(1, 1); STAGE4(2, 2);
  asm volatile("s_waitcnt vmcnt(8)" ::: "memory");
  __builtin_amdgcn_s_barrier();

  intx4 tb0, tb1, tb2, tb3;
  for (int j = 0; j < NK; ++j) {
    int slot = j & 3;
    unsigned so = (unsigned)slot * 16384u;
    unsigned aA = aByte + so, bA = bByte + so;
    bool st = (j + 3 < NK);
    int o3 = (j + 3) * 32;
    int s3 = (j + 3) & 3;
    unsigned short* a3 = As + s3 * 8192 + ldsW;
    unsigned short* b3 = Bs + s3 * 8192 + ldsW;

    // ======== phase A: issue B frags + A m0..3 reads; stage A of j+3 ======
    intx4 t0, t1, t2, t3;
    DSR(tb0, bA);
    DSR(tb1, bA + 1024u);
    DSR(tb2, bA + 2048u);
    DSR(tb3, bA + 3072u);
    DSR(t0, aA);
    DSR(t1, aA + 1024u);
    DSR(t2, aA + 2048u);
    DSR(t3, aA + 3072u);
    if (st) { gll16(aSrc0 + o3, a3); gll16(aSrc1 + o3, a3 + 4096); }
    __builtin_amdgcn_s_barrier();           // issue->wait separated by barrier
    asm volatile("s_waitcnt lgkmcnt(0)" ::: "memory");
    __builtin_amdgcn_sched_barrier(0);
    MFMA16(0, t0, t1, t2, t3);
    __builtin_amdgcn_s_barrier();

    // ======== phase B: issue A m4..7 reads; stage B of j+3; vmcnt ========
    intx4 t4, t5, t6, t7;
    DSR(t4, aA + 4096u);
    DSR(t5, aA + 5120u);
    DSR(t6, aA + 6144u);
    DSR(t7, aA + 7168u);
    if (st) { gll16(bSrc0 + o3, b3); gll16(bSrc1 + o3, b3 + 4096); }
    if (st)                  asm volatile("s_waitcnt vmcnt(8)" ::: "memory");
    else if (j + 2 < NK)     asm volatile("s_waitcnt vmcnt(4)" ::: "memory");
    else if (j + 1 < NK)     asm volatile("s_waitcnt vmcnt(0)" ::: "memory");
    __builtin_amdgcn_s_barrier();
    asm volatile("s_waitcnt lgkmcnt(0)" ::: "memory");
    __builtin_amdgcn_sched_barrier(0);
    MFMA16(4, t4, t5, t6, t7);
    __builtin_amdgcn_s_barrier();
  }
#undef STAGE4
#undef DSR
#undef MFMA16

  if (EPI == 1) {
    // fp32 output: 16 lanes x 4B = 64B segments, direct stores
#pragma unroll
    for (int i = 0; i < 8; i++) {
      int mb = bm + wm + i * 16 + quad * 4;
#pragma unroll
      for (int jj = 0; jj < 4; jj++) {
        int n = bn + wn + jj * 16 + r16;
        float bA = biasA[n];
#pragma unroll
        for (int r = 0; r < 4; r++) {
          size_t idx = (size_t)(mb + r) * N + n;
          outF[idx] = res[idx] + acc[i][jj][r] + bA;
        }
      }
    }
  } else {
    // bf16 output: stage half the tile in LDS, then coalesced 16B/lane
    // stores. Halves macro-unrolled with literal P (rule #20).
    unsigned short* sm16 = smem;   // 128 rows x 260 elems = 66.6 KB
#define EPI_HALF(P) {                                                        \
      __syncthreads(); /* P0: K-loop LDS reads done; P1: prior stores done */\
      _Pragma("unroll")                                                      \
      for (int jj = 0; jj < 4; jj++) {                                       \
        int colL = wn + jj * 16 + r16;                                       \
        int n = bn + colL;                                                   \
        _Pragma("unroll")                                                    \
        for (int i = 0; i < 4; i++) {                                        \
          int lr = (wm >> 1) + i * 16 + quad * 4;                            \
          _Pragma("unroll")                                                  \
          for (int r = 0; r < 4; r++) {                                      \
            float v = acc[(P) * 4 + i][jj][r];                               \
            float t;                                                         \
            if (EPI == 0) {                                                  \
              t = (n < 512) ? (v + biasA[n]) : sigmoidf_(v + biasB[n - 512]);\
            } else { /* EPI == 2 */                                          \
              float z = v + biasA[n];                                        \
              t = z * sigmoidf_(z);                                          \
            }                                                                \
            sm16[(lr + r) * 260 + colL] = f2bf(t);                           \
          }                                                                  \
        }                                                                    \
      }                                                                      \
      __syncthreads();                                                       \
      {                                                                      \
        int row = tid >> 2, c0 = (tid & 3) * 64;                             \
        int gr = bm + (row & 63) + ((row >> 6) * 128) + (P) * 64;            \
        const unsigned short* srcp = sm16 + row * 260 + c0;                  \
        unsigned short* gptr;                                                \
        if (EPI == 0) {                                                      \
          gptr = (bn < 512) ? (outU + (size_t)gr * 512 + bn + c0)            \
                            : (outG + (size_t)gr * 512 + (bn - 512) + c0);   \
        } else {                                                             \
          gptr = outG + (size_t)gr * N + bn + c0;                            \
        }                                                                    \
        _Pragma("unroll")                                                    \
        for (int s = 0; s < 8; s++)                                          \
          *(short8*)(gptr + s * 8) = *(const short8*)(srcp + s * 8);         \
      }                                                                      \
    }
    EPI_HALF(0)
    EPI_HALF(1)
#undef EPI_HALF
  }
}

// ---------------- Scan phase 1: per-chunk fwd/bwd aggregates ---------------
__global__ __launch_bounds__(512) void scan_phase1(const unsigned short* __restrict__ u,
    const float* __restrict__ decay, float* __restrict__ fa, float* __restrict__ ba) {
  int c = threadIdx.x, k = blockIdx.x;
  float d = decay[c];
  const unsigned short* up = u + (size_t)k * CHUNK * CDIM + c;
  float f = 0.f, bs = 0.f, p = 1.f;
#pragma unroll 8
  for (int t = 0; t < CHUNK; t++) {
    float v = bf2f(up[(size_t)t * CDIM]);
    f = d * f + v;
    bs += p * v;
    p *= d;
  }
  fa[(size_t)k * CDIM + c] = f;
  ba[(size_t)k * CDIM + c] = bs;
}

// ---------------- Scan phase 2: cross-chunk carries (fwd/bwd interleaved) --
__global__ __launch_bounds__(256) void scan_phase2(const float* __restrict__ fa,
    const float* __restrict__ ba, const float* __restrict__ decayT,
    float* __restrict__ fc, float* __restrict__ bc) {
  int c = blockIdx.x * 256 + threadIdx.x;
  float dT = decayT[c];
  float runf = 0.f, runb = 0.f;
#pragma unroll 4
  for (int k = 0; k < NCHUNK; k++) {
    int kb = NCHUNK - 1 - k;
    fc[(size_t)k * CDIM + c] = runf;
    runf = dT * runf + fa[(size_t)k * CDIM + c];
    bc[(size_t)kb * CDIM + c] = runb;
    runb = dT * runb + ba[(size_t)kb * CDIM + c];
  }
}

// ---------------- Scan phase 3: apply carries, combine, gate ---------------
__global__ __launch_bounds__(512) void scan_phase3(const unsigned short* __restrict__ u,
    const unsigned short* __restrict__ gate, const float* __restrict__ decay,
    const float* __restrict__ fc, const float* __restrict__ bc,
    unsigned short* __restrict__ state) {
  int c = threadIdx.x, k = blockIdx.x;
  float d = decay[c];
  size_t base = (size_t)k * CHUNK * CDIM + c;
  float fwd[CHUNK];
  float run = fc[(size_t)k * CDIM + c];
#pragma unroll
  for (int t = 0; t < CHUNK; t++) {
    run = d * run + bf2f(u[base + (size_t)t * CDIM]);
    fwd[t] = run;
  }
  float runb = bc[(size_t)k * CDIM + c];
#pragma unroll
  for (int t = CHUNK - 1; t >= 0; t--) {
    runb = d * runb + bf2f(u[base + (size_t)t * CDIM]);
    float g = bf2f(gate[base + (size_t)t * CDIM]);
    state[base + (size_t)t * CDIM] = f2bf(0.5f * (fwd[t] + runb) * g);
  }
}

// ---------------------------------------------------------------------------
extern "C" void kernel_launch(void* const* d_in, const int* in_sizes, int n_in,
                              void* d_out, int out_size, void* d_ws, size_t ws_size,
                              hipStream_t stream) {
  const float* x = (const float*)d_in[0];
  const float* ln1_w = (const float*)d_in[1];
  const float* ln1_b = (const float*)d_in[2];
  const float* W_in = (const float*)d_in[3];
  const float* b_in = (const float*)d_in[4];
  const float* W_gate = (const float*)d_in[5];
  const float* b_gate = (const float*)d_in[6];
  const float* W_out = (const float*)d_in[7];
  const float* b_out = (const float*)d_in[8];
  const float* decay_logit = (const float*)d_in[9];
  const float* ln2_w = (const float*)d_in[10];
  const float* ln2_b = (const float*)d_in[11];
  const float* W_ff1 = (const float*)d_in[12];
  const float* b_ff1 = (const float*)d_in[13];
  const float* W_ff2 = (const float*)d_in[14];
  const float* b_ff2 = (const float*)d_in[15];

  char* ws = (char*)d_ws;
  size_t off = 0;
  auto alloc = [&](size_t bytes) -> void* {
    void* p = ws + off;
    off += (bytes + 255) & ~(size_t)255;
    return p;
  };
  // --- small persistent buffers (~8.5 MB) ---
  unsigned short* Wt_ig  = (unsigned short*)alloc((size_t)1024 * 512 * 2);
  unsigned short* Wt_out = (unsigned short*)alloc((size_t)512 * 512 * 2);
  unsigned short* Wt_ff1 = (unsigned short*)alloc((size_t)1024 * 512 * 2);
  unsigned short* Wt_ff2 = (unsigned short*)alloc((size_t)512 * 1024 * 2);
  float* fa = (float*)alloc((size_t)NCHUNK * CDIM * 4);
  float* ba = (float*)alloc((size_t)NCHUNK * CDIM * 4);
  float* fc = (float*)alloc((size_t)NCHUNK * CDIM * 4);
  float* bc = (float*)alloc((size_t)NCHUNK * CDIM * 4);
  float* decay  = (float*)alloc(CDIM * 4);
  float* decayT = (float*)alloc(CDIM * 4);
  // --- large aliased regions (liveness-disjoint) ---
  const size_t LC2 = (size_t)L_SEQ * CDIM * 2; // 33.55 MB
  unsigned short* R1 = (unsigned short*)alloc(LC2);      // hidden -> state -> hbuf
  unsigned short* R2 = (unsigned short*)alloc(LC2);      // u(bf16) -> ffb[0:]
  unsigned short* R3 = (unsigned short*)alloc(LC2);      // gate    -> ffb[L*C:]
  unsigned short* hidden = R1;
  unsigned short* state  = R1;
  unsigned short* hbuf   = R1;
  unsigned short* u_buf  = R2;
  unsigned short* gate   = R3;
  unsigned short* ffb    = R2; // 67 MB spanning R2+R3 (contiguous)
  float* x2 = (float*)d_out;   // d_out doubles as x2 buffer

  // single prep launch: all transposes + decay
  prep_all<<<1793, 256, 0, stream>>>(W_in, W_gate, W_out, W_ff1, W_ff2,
      decay_logit, Wt_ig, Wt_out, Wt_ff1, Wt_ff2, decay, decayT);

  // LN1
  ln_kernel<<<L_SEQ / 4, 256, 0, stream>>>(x, ln1_w, ln1_b, hidden);

  // u | gate fused GEMM (N=1024); grid = (M/256, N/256)
  gemm256<0><<<dim3(L_SEQ / 256, 1024 / 256), 512, 0, stream>>>(
      hidden, Wt_ig, b_in, b_gate, nullptr, nullptr, u_buf, gate, L_SEQ, 1024, 512);

  // bidirectional scan
  scan_phase1<<<NCHUNK, 512, 0, stream>>>(u_buf, decay, fa, ba);
  scan_phase2<<<2, 256, 0, stream>>>(fa, ba, decayT, fc, bc);
  scan_phase3<<<NCHUNK, 512, 0, stream>>>(u_buf, gate, decay, fc, bc, state);

  // x2 = x + state @ W_out + b_out   (written to d_out)
  gemm256<1><<<dim3(L_SEQ / 256, 512 / 256), 512, 0, stream>>>(
      state, Wt_out, b_out, nullptr, x, x2, nullptr, nullptr, L_SEQ, 512, 512);

  // LN2
  ln_kernel<<<L_SEQ / 4, 256, 0, stream>>>(x2, ln2_w, ln2_b, hbuf);

  // ff = silu(h @ W_ff1 + b_ff1)
  gemm256<2><<<dim3(L_SEQ / 256, 1024 / 256), 512, 0, stream>>>(
      hbuf, Wt_ff1, b_ff1, nullptr, nullptr, nullptr, nullptr, ffb, L_SEQ, 1024, 512);

  // out = x2 + ff @ W_ff2 + b_ff2   (in-place read/write on d_out is per-element safe)
  gemm256<1><<<dim3(L_SEQ / 256, 512 / 256), 512, 0, stream>>>(
      ffb, Wt_ff2, b_ff2, nullptr, x2, x2, nullptr, nullptr, L_SEQ, 512, 1024);
}

// Round 5
// 466.569 us; speedup vs baseline: 1.0058x; 1.0058x over previous
//
#include <hip/hip_runtime.h>
#include <stdint.h>

// ---------------------------------------------------------------------------
// MambaLikeBlock on MI355X (gfx950)
// R11: co-residency is the lever. Evidence: m97-structure collapses 874->320
//     TF when grid gives 1 block/CU (m102 @2048); our R8-R10 256^2 kernels
//     (128KB LDS -> hard 1 block/CU) sat at 374 TF across THREE different
//     intra-block schedules (all null). Back to 128^2 tile / 256 thr /
//     acc[4][4] / 34KB LDS -> 4 blocks/CU (16 waves/CU), with the one
//     verified upgrade over R6: global_load_lds staging (m151: +35% vs
//     reg-staging at 128^2) and the T3-minimum single-barrier K-loop.
//     Inter-block TLP hides the per-iter drain (m114 mechanism).
// ---------------------------------------------------------------------------

#define L_SEQ 32768
#define CDIM 512
#define LN_EPS 1e-5f
#define CHUNK 64
#define NCHUNK (L_SEQ / CHUNK) // 512

typedef __attribute__((ext_vector_type(8))) short short8;
typedef __attribute__((ext_vector_type(4))) float floatx4;

__device__ inline unsigned short f2bf(float f) {
  union { float f; unsigned int u; } v; v.f = f;
  unsigned int r = v.u + 0x7fffu + ((v.u >> 16) & 1u);
  return (unsigned short)(r >> 16);
}
__device__ inline float bf2f(unsigned short h) {
  union { float f; unsigned int u; } v; v.u = ((unsigned int)h) << 16;
  return v.f;
}
__device__ inline float sigmoidf_(float x) { return 1.0f / (1.0f + __expf(-x)); }

// global -> LDS direct copy, 16B per lane. LDS dst = wave-uniform base +
// lane*16B (hardware); global src is per-lane (carries the swizzle).
__device__ __forceinline__ void gll16(const void* g, void* l) {
  __builtin_amdgcn_global_load_lds(
      (__attribute__((address_space(1))) void*)g,
      (__attribute__((address_space(3))) void*)l, 16, 0, 0);
}

// ---------------- LayerNorm: one wave per row (C=512 = 64 lanes x 8) -------
__global__ __launch_bounds__(256) void ln_kernel(const float* __restrict__ x,
    const float* __restrict__ w, const float* __restrict__ b,
    unsigned short* __restrict__ out) {
  int row = blockIdx.x * 4 + (threadIdx.x >> 6);
  int lane = threadIdx.x & 63;
  const float4* xr = (const float4*)(x + (size_t)row * CDIM);
  float4 v0 = xr[lane * 2];
  float4 v1 = xr[lane * 2 + 1];
  float s = v0.x + v0.y + v0.z + v0.w + v1.x + v1.y + v1.z + v1.w;
  float s2 = v0.x * v0.x + v0.y * v0.y + v0.z * v0.z + v0.w * v0.w +
             v1.x * v1.x + v1.y * v1.y + v1.z * v1.z + v1.w * v1.w;
  for (int m = 32; m > 0; m >>= 1) {
    s += __shfl_xor(s, m, 64);
    s2 += __shfl_xor(s2, m, 64);
  }
  float mean = s * (1.0f / CDIM);
  float var = s2 * (1.0f / CDIM) - mean * mean;
  float rs = rsqrtf(var + LN_EPS);
  const float4* wr = (const float4*)w;
  const float4* br = (const float4*)b;
  float4 w0 = wr[lane * 2], w1 = wr[lane * 2 + 1];
  float4 b0 = br[lane * 2], b1 = br[lane * 2 + 1];
  unsigned int p0 = (unsigned int)f2bf((v0.x - mean) * rs * w0.x + b0.x) |
                    ((unsigned int)f2bf((v0.y - mean) * rs * w0.y + b0.y) << 16);
  unsigned int p1 = (unsigned int)f2bf((v0.z - mean) * rs * w0.z + b0.z) |
                    ((unsigned int)f2bf((v0.w - mean) * rs * w0.w + b0.w) << 16);
  unsigned int p2 = (unsigned int)f2bf((v1.x - mean) * rs * w1.x + b1.x) |
                    ((unsigned int)f2bf((v1.y - mean) * rs * w1.y + b1.y) << 16);
  unsigned int p3 = (unsigned int)f2bf((v1.z - mean) * rs * w1.z + b1.z) |
                    ((unsigned int)f2bf((v1.w - mean) * rs * w1.w + b1.w) << 16);
  uint4 pk; pk.x = p0; pk.y = p1; pk.z = p2; pk.w = p3;
  *((uint4*)(out + (size_t)row * CDIM + lane * 8)) = pk;
}

// ---------------- Combined prep: 5 weight transposes + decay (1 launch) ----
__global__ __launch_bounds__(256) void prep_all(
    const float* __restrict__ W_in, const float* __restrict__ W_gate,
    const float* __restrict__ W_out, const float* __restrict__ W_ff1,
    const float* __restrict__ W_ff2, const float* __restrict__ logit,
    unsigned short* __restrict__ Wt_ig, unsigned short* __restrict__ Wt_out,
    unsigned short* __restrict__ Wt_ff1, unsigned short* __restrict__ Wt_ff2,
    float* __restrict__ decay, float* __restrict__ decayT) {
  int b = blockIdx.x;
  if (b >= 1792) { // decay prep
    for (int c = threadIdx.x; c < CDIM; c += 256) {
      float d = sigmoidf_(logit[c]);
      decay[c] = d;
      float p = d;
      for (int i = 0; i < 6; i++) p *= p; // d^64
      decayT[c] = p;
    }
    return;
  }
  const float* W; unsigned short* Wt; int Kd, Nd, t;
  if (b < 256)       { W = W_in;   Wt = Wt_ig;             Kd = 512;  Nd = 512;  t = b; }
  else if (b < 512)  { W = W_gate; Wt = Wt_ig + 512 * 512; Kd = 512;  Nd = 512;  t = b - 256; }
  else if (b < 768)  { W = W_out;  Wt = Wt_out;            Kd = 512;  Nd = 512;  t = b - 512; }
  else if (b < 1280) { W = W_ff1;  Wt = Wt_ff1;            Kd = 512;  Nd = 1024; t = b - 768; }
  else               { W = W_ff2;  Wt = Wt_ff2;            Kd = 1024; Nd = 512;  t = b - 1280; }
  int ntx = Nd >> 5;
  int n0 = (t % ntx) * 32, k0 = (t / ntx) * 32;
  __shared__ float tile[32][33];
  int tx = threadIdx.x & 31, ty = threadIdx.x >> 5; // 32x8
  for (int r = 0; r < 32; r += 8)
    tile[ty + r][tx] = W[(size_t)(k0 + ty + r) * Nd + n0 + tx];
  __syncthreads();
  for (int r = 0; r < 32; r += 8)
    Wt[(size_t)(n0 + ty + r) * Kd + k0 + tx] = f2bf(tile[tx][ty + r]);
}

// ---------------- bf16 MFMA GEMM: C = A(MxK) * Bt(NxK)^T + epilogue --------
// 128x128 tile, 256 threads = 4 waves (2x2), per-wave 64x64 output
// (4x4 16x16 frags, 64 VGPR acc). BK=32. LDS: 2-buffer staging (2 x 16 KB)
// aliased with 34 KB bf16 epilogue tile -> 4 blocks/CU, 16 waves/CU.
// K-loop (T3 minimum): {stage nxt via 4x global_load_lds -> ds_read cur ->
// 16 MFMA -> vmcnt(0)+barrier}. Per-iter drain hidden by 3 foreign blocks.
// EPI 0: n<512 -> outU(bf16) = v+biasA[n]; n>=512 -> outG(bf16)=sigmoid(v+biasB)
// EPI 1: outF = res + v + biasA[n]           (float out, direct stores)
// EPI 2: outG = bf16(silu(v + biasA[n]))     (bf16 out, staged)
template <int EPI>
__global__ __launch_bounds__(256, 4) void gemm_bt(
    const unsigned short* __restrict__ A, const unsigned short* __restrict__ Bt,
    const float* __restrict__ biasA, const float* __restrict__ biasB,
    const float* __restrict__ res, float* __restrict__ outF,
    unsigned short* __restrict__ outU, unsigned short* __restrict__ outG,
    int M, int N, int K) {
  // 34 KB shared: K-loop staging (32 KB) aliased with bf16 epilogue tile.
  __shared__ char smemRaw[34048];
  unsigned short* As = (unsigned short*)smemRaw;            // 2 bufs x 4096 elems
  unsigned short* Bs = (unsigned short*)(smemRaw + 16384);  // 2 bufs x 4096 elems

  // XCD-aware remap: grid = (M/128, N/128); XCD = bid % 8. Blocks sharing an
  // A panel run consecutively on the same XCD (bn fastest within an XCD).
  int nbx = gridDim.x, nby = gridDim.y;
  int bid = blockIdx.x + blockIdx.y * nbx;
  int per = (nbx * nby) >> 3;
  int w = (bid & 7) * per + (bid >> 3);
  int ni = w % nby;
  int mi = w / nby;
  int bm = mi << 7, bn = ni << 7;

  int tid = threadIdx.x, wave = tid >> 6, lane = tid & 63;
  int wm = (wave >> 1) * 64, wn = (wave & 1) * 64;

  // staging addressing (R6-verified swizzled layout; measured 0 conflicts)
  int srow = wave * 16 + (lane >> 2);
  int chunkSel = (lane & 3) ^ ((lane >> 3) & 3);
  int scol = chunkSel * 8;
  const unsigned short* aP0 = A + (size_t)(bm + srow) * K + scol;
  const unsigned short* aP1 = A + (size_t)(bm + 64 + srow) * K + scol;
  const unsigned short* bP0 = Bt + (size_t)(bn + srow) * K + scol;
  const unsigned short* bP1 = Bt + (size_t)(bn + 64 + srow) * K + scol;
  int wbase = wave * 512; // wave-uniform LDS elem offset; HW adds lane*16B

#define STAGE(bufOff, ktile) do {                                 \
    int _o = (ktile) * 32;                                        \
    gll16(aP0 + _o, As + (bufOff) + wbase);                       \
    gll16(aP1 + _o, As + (bufOff) + 2048 + wbase);                \
    gll16(bP0 + _o, Bs + (bufOff) + wbase);                       \
    gll16(bP1 + _o, Bs + (bufOff) + 2048 + wbase);                \
  } while (0)

  floatx4 acc[4][4];
#pragma unroll
  for (int i = 0; i < 4; i++)
#pragma unroll
    for (int j = 0; j < 4; j++) acc[i][j] = (floatx4){0.f, 0.f, 0.f, 0.f};

  int quad = lane >> 4, r16 = lane & 15;
  int cSwz = ((quad ^ (r16 >> 1)) & 3) * 8; // inverse of staging swizzle

  int NK = K >> 5;

  // prologue: tile 0 -> buf0 (syncthreads drains vmcnt -> visible to all)
  STAGE(0, 0);
  asm volatile("s_waitcnt vmcnt(0)" ::: "memory");
  __syncthreads();

  for (int k = 0; k < NK; ++k) {
    int cur = (k & 1) * 4096, nxt = cur ^ 4096;
    if (k + 1 < NK) STAGE(nxt, k + 1);  // prefetch next tile into other buf
    short8 af[4], bfm[4];
#pragma unroll
    for (int i = 0; i < 4; i++)
      af[i] = *(const short8*)(&As[cur + (wm + i * 16 + r16) * 32 + cSwz]);
#pragma unroll
    for (int j = 0; j < 4; j++)
      bfm[j] = *(const short8*)(&Bs[cur + (wn + j * 16 + r16) * 32 + cSwz]);
#pragma unroll
    for (int i = 0; i < 4; i++)
#pragma unroll
      for (int j = 0; j < 4; j++)
        acc[i][j] = __builtin_amdgcn_mfma_f32_16x16x32_bf16(af[i], bfm[j], acc[i][j], 0, 0, 0);
    // drain this iter's stage (next iter reads nxt) + protect cur from
    // being overwritten before all waves finished reading it.
    asm volatile("s_waitcnt vmcnt(0)" ::: "memory");
    __syncthreads();
  }
#undef STAGE

  if (EPI == 1) {
    // fp32 output: 16 lanes x 4B = 64B aligned segments, direct stores
#pragma unroll
    for (int j = 0; j < 4; j++) {
      int n = bn + wn + j * 16 + r16;
#pragma unroll
      for (int i = 0; i < 4; i++) {
        int mb = bm + wm + i * 16 + quad * 4;
#pragma unroll
        for (int r = 0; r < 4; r++) {
          size_t idx = (size_t)(mb + r) * N + n;
          outF[idx] = res[idx] + acc[i][j][r] + biasA[n];
        }
      }
    }
  } else {
    // bf16 output: stage tile in LDS, then coalesced 16B/lane stores
    unsigned short* sm = (unsigned short*)smemRaw;
#pragma unroll
    for (int j = 0; j < 4; j++) {
      int n = bn + wn + j * 16 + r16;
      int ln = wn + j * 16 + r16;
#pragma unroll
      for (int i = 0; i < 4; i++) {
        int lmb = wm + i * 16 + quad * 4;
#pragma unroll
        for (int r = 0; r < 4; r++) {
          float v = acc[i][j][r];
          float t;
          if (EPI == 0) {
            t = (n < 512) ? (v + biasA[n]) : sigmoidf_(v + biasB[n - 512]);
          } else { // EPI == 2
            float z = v + biasA[n];
            t = z * sigmoidf_(z);
          }
          sm[(lmb + r) * 132 + ln] = f2bf(t);
        }
      }
    }
    __syncthreads();
    int row = tid >> 1, half = tid & 1;
    const unsigned short* src = sm + row * 132 + half * 64;
    unsigned short* gptr;
    if (EPI == 0) {
      gptr = ((bn < 512) ? outU : (outG - 512)) + (size_t)(bm + row) * 512 + bn + half * 64;
    } else {
      gptr = outG + (size_t)(bm + row) * N + bn + half * 64;
    }
#pragma unroll
    for (int s = 0; s < 8; s++)
      *(short8*)(gptr + s * 8) = *(const short8*)(src + s * 8);
  }
}

// ---------------- Scan phase 1: per-chunk fwd/bwd aggregates ---------------
__global__ __launch_bounds__(512) void scan_phase1(const unsigned short* __restrict__ u,
    const float* __restrict__ decay, float* __restrict__ fa, float* __restrict__ ba) {
  int c = threadIdx.x, k = blockIdx.x;
  float d = decay[c];
  const unsigned short* up = u + (size_t)k * CHUNK * CDIM + c;
  float f = 0.f, bs = 0.f, p = 1.f;
#pragma unroll 8
  for (int t = 0; t < CHUNK; t++) {
    float v = bf2f(up[(size_t)t * CDIM]);
    f = d * f + v;
    bs += p * v;
    p *= d;
  }
  fa[(size_t)k * CDIM + c] = f;
  ba[(size_t)k * CDIM + c] = bs;
}

// ---------------- Scan phase 2: cross-chunk carries (fwd/bwd interleaved) --
__global__ __launch_bounds__(256) void scan_phase2(const float* __restrict__ fa,
    const float* __restrict__ ba, const float* __restrict__ decayT,
    float* __restrict__ fc, float* __restrict__ bc) {
  int c = blockIdx.x * 256 + threadIdx.x;
  float dT = decayT[c];
  float runf = 0.f, runb = 0.f;
#pragma unroll 4
  for (int k = 0; k < NCHUNK; k++) {
    int kb = NCHUNK - 1 - k;
    fc[(size_t)k * CDIM + c] = runf;
    runf = dT * runf + fa[(size_t)k * CDIM + c];
    bc[(size_t)kb * CDIM + c] = runb;
    runb = dT * runb + ba[(size_t)kb * CDIM + c];
  }
}

// ---------------- Scan phase 3: apply carries, combine, gate ---------------
__global__ __launch_bounds__(512) void scan_phase3(const unsigned short* __restrict__ u,
    const unsigned short* __restrict__ gate, const float* __restrict__ decay,
    const float* __restrict__ fc, const float* __restrict__ bc,
    unsigned short* __restrict__ state) {
  int c = threadIdx.x, k = blockIdx.x;
  float d = decay[c];
  size_t base = (size_t)k * CHUNK * CDIM + c;
  float fwd[CHUNK];
  float run = fc[(size_t)k * CDIM + c];
#pragma unroll
  for (int t = 0; t < CHUNK; t++) {
    run = d * run + bf2f(u[base + (size_t)t * CDIM]);
    fwd[t] = run;
  }
  float runb = bc[(size_t)k * CDIM + c];
#pragma unroll
  for (int t = CHUNK - 1; t >= 0; t--) {
    runb = d * runb + bf2f(u[base + (size_t)t * CDIM]);
    float g = bf2f(gate[base + (size_t)t * CDIM]);
    state[base + (size_t)t * CDIM] = f2bf(0.5f * (fwd[t] + runb) * g);
  }
}

// ---------------------------------------------------------------------------
extern "C" void kernel_launch(void* const* d_in, const int* in_sizes, int n_in,
                              void* d_out, int out_size, void* d_ws, size_t ws_size,
                              hipStream_t stream) {
  const float* x = (const float*)d_in[0];
  const float* ln1_w = (const float*)d_in[1];
  const float* ln1_b = (const float*)d_in[2];
  const float* W_in = (const float*)d_in[3];
  const float* b_in = (const float*)d_in[4];
  const float* W_gate = (const float*)d_in[5];
  const float* b_gate = (const float*)d_in[6];
  const float* W_out = (const float*)d_in[7];
  const float* b_out = (const float*)d_in[8];
  const float* decay_logit = (const float*)d_in[9];
  const float* ln2_w = (const float*)d_in[10];
  const float* ln2_b = (const float*)d_in[11];
  const float* W_ff1 = (const float*)d_in[12];
  const float* b_ff1 = (const float*)d_in[13];
  const float* W_ff2 = (const float*)d_in[14];
  const float* b_ff2 = (const float*)d_in[15];

  char* ws = (char*)d_ws;
  size_t off = 0;
  auto alloc = [&](size_t bytes) -> void* {
    void* p = ws + off;
    off += (bytes + 255) & ~(size_t)255;
    return p;
  };
  // --- small persistent buffers (~8.5 MB) ---
  unsigned short* Wt_ig  = (unsigned short*)alloc((size_t)1024 * 512 * 2);
  unsigned short* Wt_out = (unsigned short*)alloc((size_t)512 * 512 * 2);
  unsigned short* Wt_ff1 = (unsigned short*)alloc((size_t)1024 * 512 * 2);
  unsigned short* Wt_ff2 = (unsigned short*)alloc((size_t)512 * 1024 * 2);
  float* fa = (float*)alloc((size_t)NCHUNK * CDIM * 4);
  float* ba = (float*)alloc((size_t)NCHUNK * CDIM * 4);
  float* fc = (float*)alloc((size_t)NCHUNK * CDIM * 4);
  float* bc = (float*)alloc((size_t)NCHUNK * CDIM * 4);
  float* decay  = (float*)alloc(CDIM * 4);
  float* decayT = (float*)alloc(CDIM * 4);
  // --- large aliased regions (liveness-disjoint) ---
  const size_t LC2 = (size_t)L_SEQ * CDIM * 2; // 33.55 MB
  unsigned short* R1 = (unsigned short*)alloc(LC2);      // hidden -> state -> hbuf
  unsigned short* R2 = (unsigned short*)alloc(LC2);      // u(bf16) -> ffb[0:]
  unsigned short* R3 = (unsigned short*)alloc(LC2);      // gate    -> ffb[L*C:]
  unsigned short* hidden = R1;
  unsigned short* state  = R1;
  unsigned short* hbuf   = R1;
  unsigned short* u_buf  = R2;
  unsigned short* gate   = R3;
  unsigned short* ffb    = R2; // 67 MB spanning R2+R3 (contiguous)
  float* x2 = (float*)d_out;   // d_out doubles as x2 buffer

  // single prep launch: all transposes + decay
  prep_all<<<1793, 256, 0, stream>>>(W_in, W_gate, W_out, W_ff1, W_ff2,
      decay_logit, Wt_ig, Wt_out, Wt_ff1, Wt_ff2, decay, decayT);

  // LN1
  ln_kernel<<<L_SEQ / 4, 256, 0, stream>>>(x, ln1_w, ln1_b, hidden);

  // u | gate fused GEMM (N=1024); grid = (M/128, N/128)
  gemm_bt<0><<<dim3(L_SEQ / 128, 1024 / 128), 256, 0, stream>>>(
      hidden, Wt_ig, b_in, b_gate, nullptr, nullptr, u_buf, gate, L_SEQ, 1024, 512);

  // bidirectional scan
  scan_phase1<<<NCHUNK, 512, 0, stream>>>(u_buf, decay, fa, ba);
  scan_phase2<<<2, 256, 0, stream>>>(fa, ba, decayT, fc, bc);
  scan_phase3<<<NCHUNK, 512, 0, stream>>>(u_buf, gate, decay, fc, bc, state);

  // x2 = x + state @ W_out + b_out   (written to d_out)
  gemm_bt<1><<<dim3(L_SEQ / 128, 512 / 128), 256, 0, stream>>>(
      state, Wt_out, b_out, nullptr, x, x2, nullptr, nullptr, L_SEQ, 512, 512);

  // LN2
  ln_kernel<<<L_SEQ / 4, 256, 0, stream>>>(x2, ln2_w, ln2_b, hbuf);

  // ff = silu(h @ W_ff1 + b_ff1)
  gemm_bt<2><<<dim3(L_SEQ / 128, 1024 / 128), 256, 0, stream>>>(
      hbuf, Wt_ff1, b_ff1, nullptr, nullptr, nullptr, nullptr, ffb, L_SEQ, 1024, 512);

  // out = x2 + ff @ W_ff2 + b_ff2   (in-place read/write on d_out is per-element safe)
  gemm_bt<1><<<dim3(L_SEQ / 128, 512 / 128), 256, 0, stream>>>(
      ffb, Wt_ff2, b_ff2, nullptr, x2, x2, nullptr, nullptr, L_SEQ, 512, 1024);
}

// Round 6
// 431.381 us; speedup vs baseline: 1.0878x; 1.0816x over previous
//
#include <hip/hip_runtime.h>
#include <stdint.h>

// ---------------------------------------------------------------------------
// MambaLikeBlock on MI355X (gfx950)
// R12: non-GEMM was ~190us of 466 (GEMMs ~277 at R11's 79us best). Fixes:
//  (a) scan_phase2 (2-block serial 512-iter dependent loop, ~40us) ->
//      hierarchical 3-level scan: p2a 16-way parallel group-local carries,
//      p2b tiny 16-step group recurrence, phase3 reconstructs
//      carry = local + dT^j * G[g] (exact linear-recurrence reassociation).
//  (b) scan_phase3 caches u in registers (packed bf16 pairs, static idx)
//      -> eliminates the 64MB second read of u.
//  GEMM kept at R11 structure (128^2, 4 blocks/CU, gload_lds dbuf).
// ---------------------------------------------------------------------------

#define L_SEQ 32768
#define CDIM 512
#define LN_EPS 1e-5f
#define CHUNK 64
#define NCHUNK (L_SEQ / CHUNK) // 512
#define NGRP 16
#define GCHUNK (NCHUNK / NGRP) // 32

typedef __attribute__((ext_vector_type(8))) short short8;
typedef __attribute__((ext_vector_type(4))) float floatx4;

__device__ inline unsigned short f2bf(float f) {
  union { float f; unsigned int u; } v; v.f = f;
  unsigned int r = v.u + 0x7fffu + ((v.u >> 16) & 1u);
  return (unsigned short)(r >> 16);
}
__device__ inline float bf2f(unsigned short h) {
  union { float f; unsigned int u; } v; v.u = ((unsigned int)h) << 16;
  return v.f;
}
__device__ inline float sigmoidf_(float x) { return 1.0f / (1.0f + __expf(-x)); }

// dT^e for e in [0,31], 5 square-and-multiply steps
__device__ inline float powi5(float s, int e) {
  float p = 1.f;
#pragma unroll
  for (int b = 0; b < 5; b++) { if (e & (1 << b)) p *= s; s *= s; }
  return p;
}

// global -> LDS direct copy, 16B per lane.
__device__ __forceinline__ void gll16(const void* g, void* l) {
  __builtin_amdgcn_global_load_lds(
      (__attribute__((address_space(1))) void*)g,
      (__attribute__((address_space(3))) void*)l, 16, 0, 0);
}

// ---------------- LayerNorm: one wave per row (C=512 = 64 lanes x 8) -------
__global__ __launch_bounds__(256) void ln_kernel(const float* __restrict__ x,
    const float* __restrict__ w, const float* __restrict__ b,
    unsigned short* __restrict__ out) {
  int row = blockIdx.x * 4 + (threadIdx.x >> 6);
  int lane = threadIdx.x & 63;
  const float4* xr = (const float4*)(x + (size_t)row * CDIM);
  float4 v0 = xr[lane * 2];
  float4 v1 = xr[lane * 2 + 1];
  float s = v0.x + v0.y + v0.z + v0.w + v1.x + v1.y + v1.z + v1.w;
  float s2 = v0.x * v0.x + v0.y * v0.y + v0.z * v0.z + v0.w * v0.w +
             v1.x * v1.x + v1.y * v1.y + v1.z * v1.z + v1.w * v1.w;
  for (int m = 32; m > 0; m >>= 1) {
    s += __shfl_xor(s, m, 64);
    s2 += __shfl_xor(s2, m, 64);
  }
  float mean = s * (1.0f / CDIM);
  float var = s2 * (1.0f / CDIM) - mean * mean;
  float rs = rsqrtf(var + LN_EPS);
  const float4* wr = (const float4*)w;
  const float4* br = (const float4*)b;
  float4 w0 = wr[lane * 2], w1 = wr[lane * 2 + 1];
  float4 b0 = br[lane * 2], b1 = br[lane * 2 + 1];
  unsigned int p0 = (unsigned int)f2bf((v0.x - mean) * rs * w0.x + b0.x) |
                    ((unsigned int)f2bf((v0.y - mean) * rs * w0.y + b0.y) << 16);
  unsigned int p1 = (unsigned int)f2bf((v0.z - mean) * rs * w0.z + b0.z) |
                    ((unsigned int)f2bf((v0.w - mean) * rs * w0.w + b0.w) << 16);
  unsigned int p2 = (unsigned int)f2bf((v1.x - mean) * rs * w1.x + b1.x) |
                    ((unsigned int)f2bf((v1.y - mean) * rs * w1.y + b1.y) << 16);
  unsigned int p3 = (unsigned int)f2bf((v1.z - mean) * rs * w1.z + b1.z) |
                    ((unsigned int)f2bf((v1.w - mean) * rs * w1.w + b1.w) << 16);
  uint4 pk; pk.x = p0; pk.y = p1; pk.z = p2; pk.w = p3;
  *((uint4*)(out + (size_t)row * CDIM + lane * 8)) = pk;
}

// ---------------- Combined prep: 5 weight transposes + decay (1 launch) ----
__global__ __launch_bounds__(256) void prep_all(
    const float* __restrict__ W_in, const float* __restrict__ W_gate,
    const float* __restrict__ W_out, const float* __restrict__ W_ff1,
    const float* __restrict__ W_ff2, const float* __restrict__ logit,
    unsigned short* __restrict__ Wt_ig, unsigned short* __restrict__ Wt_out,
    unsigned short* __restrict__ Wt_ff1, unsigned short* __restrict__ Wt_ff2,
    float* __restrict__ decay, float* __restrict__ decayT) {
  int b = blockIdx.x;
  if (b >= 1792) { // decay prep
    for (int c = threadIdx.x; c < CDIM; c += 256) {
      float d = sigmoidf_(logit[c]);
      decay[c] = d;
      float p = d;
      for (int i = 0; i < 6; i++) p *= p; // d^64
      decayT[c] = p;
    }
    return;
  }
  const float* W; unsigned short* Wt; int Kd, Nd, t;
  if (b < 256)       { W = W_in;   Wt = Wt_ig;             Kd = 512;  Nd = 512;  t = b; }
  else if (b < 512)  { W = W_gate; Wt = Wt_ig + 512 * 512; Kd = 512;  Nd = 512;  t = b - 256; }
  else if (b < 768)  { W = W_out;  Wt = Wt_out;            Kd = 512;  Nd = 512;  t = b - 512; }
  else if (b < 1280) { W = W_ff1;  Wt = Wt_ff1;            Kd = 512;  Nd = 1024; t = b - 768; }
  else               { W = W_ff2;  Wt = Wt_ff2;            Kd = 1024; Nd = 512;  t = b - 1280; }
  int ntx = Nd >> 5;
  int n0 = (t % ntx) * 32, k0 = (t / ntx) * 32;
  __shared__ float tile[32][33];
  int tx = threadIdx.x & 31, ty = threadIdx.x >> 5; // 32x8
  for (int r = 0; r < 32; r += 8)
    tile[ty + r][tx] = W[(size_t)(k0 + ty + r) * Nd + n0 + tx];
  __syncthreads();
  for (int r = 0; r < 32; r += 8)
    Wt[(size_t)(n0 + ty + r) * Kd + k0 + tx] = f2bf(tile[tx][ty + r]);
}

// ---------------- bf16 MFMA GEMM: C = A(MxK) * Bt(NxK)^T + epilogue --------
// (R11 structure: 128x128 tile, 4 waves, 34KB LDS, 4 blocks/CU, gload_lds
// double-buffer, one drain+barrier per K-step.)
template <int EPI>
__global__ __launch_bounds__(256, 4) void gemm_bt(
    const unsigned short* __restrict__ A, const unsigned short* __restrict__ Bt,
    const float* __restrict__ biasA, const float* __restrict__ biasB,
    const float* __restrict__ res, float* __restrict__ outF,
    unsigned short* __restrict__ outU, unsigned short* __restrict__ outG,
    int M, int N, int K) {
  __shared__ char smemRaw[34048];
  unsigned short* As = (unsigned short*)smemRaw;            // 2 bufs x 4096 elems
  unsigned short* Bs = (unsigned short*)(smemRaw + 16384);  // 2 bufs x 4096 elems

  int nbx = gridDim.x, nby = gridDim.y;
  int bid = blockIdx.x + blockIdx.y * nbx;
  int per = (nbx * nby) >> 3;
  int w = (bid & 7) * per + (bid >> 3);
  int ni = w % nby;
  int mi = w / nby;
  int bm = mi << 7, bn = ni << 7;

  int tid = threadIdx.x, wave = tid >> 6, lane = tid & 63;
  int wm = (wave >> 1) * 64, wn = (wave & 1) * 64;

  int srow = wave * 16 + (lane >> 2);
  int chunkSel = (lane & 3) ^ ((lane >> 3) & 3);
  int scol = chunkSel * 8;
  const unsigned short* aP0 = A + (size_t)(bm + srow) * K + scol;
  const unsigned short* aP1 = A + (size_t)(bm + 64 + srow) * K + scol;
  const unsigned short* bP0 = Bt + (size_t)(bn + srow) * K + scol;
  const unsigned short* bP1 = Bt + (size_t)(bn + 64 + srow) * K + scol;
  int wbase = wave * 512;

#define STAGE(bufOff, ktile) do {                                 \
    int _o = (ktile) * 32;                                        \
    gll16(aP0 + _o, As + (bufOff) + wbase);                       \
    gll16(aP1 + _o, As + (bufOff) + 2048 + wbase);                \
    gll16(bP0 + _o, Bs + (bufOff) + wbase);                       \
    gll16(bP1 + _o, Bs + (bufOff) + 2048 + wbase);                \
  } while (0)

  floatx4 acc[4][4];
#pragma unroll
  for (int i = 0; i < 4; i++)
#pragma unroll
    for (int j = 0; j < 4; j++) acc[i][j] = (floatx4){0.f, 0.f, 0.f, 0.f};

  int quad = lane >> 4, r16 = lane & 15;
  int cSwz = ((quad ^ (r16 >> 1)) & 3) * 8;

  int NK = K >> 5;

  STAGE(0, 0);
  asm volatile("s_waitcnt vmcnt(0)" ::: "memory");
  __syncthreads();

  for (int k = 0; k < NK; ++k) {
    int cur = (k & 1) * 4096, nxt = cur ^ 4096;
    if (k + 1 < NK) STAGE(nxt, k + 1);
    short8 af[4], bfm[4];
#pragma unroll
    for (int i = 0; i < 4; i++)
      af[i] = *(const short8*)(&As[cur + (wm + i * 16 + r16) * 32 + cSwz]);
#pragma unroll
    for (int j = 0; j < 4; j++)
      bfm[j] = *(const short8*)(&Bs[cur + (wn + j * 16 + r16) * 32 + cSwz]);
#pragma unroll
    for (int i = 0; i < 4; i++)
#pragma unroll
      for (int j = 0; j < 4; j++)
        acc[i][j] = __builtin_amdgcn_mfma_f32_16x16x32_bf16(af[i], bfm[j], acc[i][j], 0, 0, 0);
    asm volatile("s_waitcnt vmcnt(0)" ::: "memory");
    __syncthreads();
  }
#undef STAGE

  if (EPI == 1) {
#pragma unroll
    for (int j = 0; j < 4; j++) {
      int n = bn + wn + j * 16 + r16;
#pragma unroll
      for (int i = 0; i < 4; i++) {
        int mb = bm + wm + i * 16 + quad * 4;
#pragma unroll
        for (int r = 0; r < 4; r++) {
          size_t idx = (size_t)(mb + r) * N + n;
          outF[idx] = res[idx] + acc[i][j][r] + biasA[n];
        }
      }
    }
  } else {
    unsigned short* sm = (unsigned short*)smemRaw;
#pragma unroll
    for (int j = 0; j < 4; j++) {
      int n = bn + wn + j * 16 + r16;
      int ln = wn + j * 16 + r16;
#pragma unroll
      for (int i = 0; i < 4; i++) {
        int lmb = wm + i * 16 + quad * 4;
#pragma unroll
        for (int r = 0; r < 4; r++) {
          float v = acc[i][j][r];
          float t;
          if (EPI == 0) {
            t = (n < 512) ? (v + biasA[n]) : sigmoidf_(v + biasB[n - 512]);
          } else { // EPI == 2
            float z = v + biasA[n];
            t = z * sigmoidf_(z);
          }
          sm[(lmb + r) * 132 + ln] = f2bf(t);
        }
      }
    }
    __syncthreads();
    int row = tid >> 1, half = tid & 1;
    const unsigned short* src = sm + row * 132 + half * 64;
    unsigned short* gptr;
    if (EPI == 0) {
      gptr = ((bn < 512) ? outU : (outG - 512)) + (size_t)(bm + row) * 512 + bn + half * 64;
    } else {
      gptr = outG + (size_t)(bm + row) * N + bn + half * 64;
    }
#pragma unroll
    for (int s = 0; s < 8; s++)
      *(short8*)(gptr + s * 8) = *(const short8*)(src + s * 8);
  }
}

// ---------------- Scan phase 1: per-chunk fwd/bwd aggregates ---------------
__global__ __launch_bounds__(512) void scan_phase1(const unsigned short* __restrict__ u,
    const float* __restrict__ decay, float* __restrict__ fa, float* __restrict__ ba) {
  int c = threadIdx.x, k = blockIdx.x;
  float d = decay[c];
  const unsigned short* up = u + (size_t)k * CHUNK * CDIM + c;
  float f = 0.f, bs = 0.f, p = 1.f;
#pragma unroll 8
  for (int t = 0; t < CHUNK; t++) {
    float v = bf2f(up[(size_t)t * CDIM]);
    f = d * f + v;
    bs += p * v;
    p *= d;
  }
  fa[(size_t)k * CDIM + c] = f;
  ba[(size_t)k * CDIM + c] = bs;
}

// ---------------- Scan phase 2a: group-local carries + group aggregates ----
// Group g = chunks [g*32, g*32+32). Writes (in-place layout):
//   fc[k] = local fwd carry into chunk k (zero-based within group)
//   bc[k] = local bwd carry into chunk k from above (within group)
//   gaF[g][c] = sum_j dT^(31-j) fa[g*32+j]   (fwd group aggregate)
//   gaB[g][c] = sum_j dT^j     ba[g*32+j]   (bwd group aggregate)
__global__ __launch_bounds__(512) void scan_p2a(const float* __restrict__ fa,
    const float* __restrict__ ba, const float* __restrict__ decayT,
    float* __restrict__ fc, float* __restrict__ bc,
    float* __restrict__ gaF, float* __restrict__ gaB) {
  int c = threadIdx.x, g = blockIdx.x;
  float dT = decayT[c];
  int k0 = g * GCHUNK;
  float runf = 0.f;
#pragma unroll 4
  for (int j = 0; j < GCHUNK; j++) {
    size_t idx = (size_t)(k0 + j) * CDIM + c;
    fc[idx] = runf;
    runf = dT * runf + fa[idx];
  }
  gaF[(size_t)g * CDIM + c] = runf;
  float runb = 0.f;
#pragma unroll 4
  for (int j = GCHUNK - 1; j >= 0; j--) {
    size_t idx = (size_t)(k0 + j) * CDIM + c;
    bc[idx] = runb;
    runb = dT * runb + ba[idx];
  }
  gaB[(size_t)g * CDIM + c] = runb;
}

// ---------------- Scan phase 2b: 16-step group recurrence ------------------
// GF[g] = global fwd carry entering group g; GB[g] = global bwd carry
// entering group g from above. Multiplier across a group = dT^32.
__global__ __launch_bounds__(512) void scan_p2b(const float* __restrict__ gaF,
    const float* __restrict__ gaB, const float* __restrict__ decayT,
    float* __restrict__ GF, float* __restrict__ GB) {
  int c = threadIdx.x;
  float dT = decayT[c];
  float d32 = dT;
#pragma unroll
  for (int i = 0; i < 5; i++) d32 *= d32;  // dT^32
  float gf = 0.f;
#pragma unroll
  for (int g = 0; g < NGRP; g++) {
    GF[(size_t)g * CDIM + c] = gf;
    gf = d32 * gf + gaF[(size_t)g * CDIM + c];
  }
  float gb = 0.f;
#pragma unroll
  for (int g = NGRP - 1; g >= 0; g--) {
    GB[(size_t)g * CDIM + c] = gb;
    gb = d32 * gb + gaB[(size_t)g * CDIM + c];
  }
}

// ---------------- Scan phase 3: apply carries, combine, gate ---------------
// Carry reconstruction: fwd carry into chunk k (k = g*32+j):
//   R_k = fc_loc[k] + dT^j * GF[g];  bwd: bc_loc[k] + dT^(31-j) * GB[g].
// u cached in registers (packed bf16 pairs, static indices) to avoid the
// second 64MB global read in the bwd loop.
__global__ __launch_bounds__(512) void scan_phase3(const unsigned short* __restrict__ u,
    const unsigned short* __restrict__ gate, const float* __restrict__ decay,
    const float* __restrict__ decayT, const float* __restrict__ fc,
    const float* __restrict__ bc, const float* __restrict__ GF,
    const float* __restrict__ GB, unsigned short* __restrict__ state) {
  int c = threadIdx.x, k = blockIdx.x;
  int g = k >> 5, j = k & 31;
  float d = decay[c];
  float dT = decayT[c];
  size_t base = (size_t)k * CHUNK * CDIM + c;
  size_t kc = (size_t)k * CDIM + c;
  size_t gc = (size_t)g * CDIM + c;
  float run  = fc[kc] + powi5(dT, j) * GF[gc];
  float runb0 = bc[kc] + powi5(dT, 31 - j) * GB[gc];
  float fwd[CHUNK];
  unsigned int us[CHUNK / 2];
#pragma unroll
  for (int t = 0; t < CHUNK; t++) {
    unsigned short uv = u[base + (size_t)t * CDIM];
    if (t & 1) us[t >> 1] |= ((unsigned int)uv) << 16;
    else       us[t >> 1] = uv;
    run = d * run + bf2f(uv);
    fwd[t] = run;
  }
  float runb = runb0;
#pragma unroll
  for (int t = CHUNK - 1; t >= 0; t--) {
    unsigned short uv = (unsigned short)((us[t >> 1] >> ((t & 1) * 16)) & 0xffffu);
    runb = d * runb + bf2f(uv);
    float gv = bf2f(gate[base + (size_t)t * CDIM]);
    state[base + (size_t)t * CDIM] = f2bf(0.5f * (fwd[t] + runb) * gv);
  }
}

// ---------------------------------------------------------------------------
extern "C" void kernel_launch(void* const* d_in, const int* in_sizes, int n_in,
                              void* d_out, int out_size, void* d_ws, size_t ws_size,
                              hipStream_t stream) {
  const float* x = (const float*)d_in[0];
  const float* ln1_w = (const float*)d_in[1];
  const float* ln1_b = (const float*)d_in[2];
  const float* W_in = (const float*)d_in[3];
  const float* b_in = (const float*)d_in[4];
  const float* W_gate = (const float*)d_in[5];
  const float* b_gate = (const float*)d_in[6];
  const float* W_out = (const float*)d_in[7];
  const float* b_out = (const float*)d_in[8];
  const float* decay_logit = (const float*)d_in[9];
  const float* ln2_w = (const float*)d_in[10];
  const float* ln2_b = (const float*)d_in[11];
  const float* W_ff1 = (const float*)d_in[12];
  const float* b_ff1 = (const float*)d_in[13];
  const float* W_ff2 = (const float*)d_in[14];
  const float* b_ff2 = (const float*)d_in[15];

  char* ws = (char*)d_ws;
  size_t off = 0;
  auto alloc = [&](size_t bytes) -> void* {
    void* p = ws + off;
    off += (bytes + 255) & ~(size_t)255;
    return p;
  };
  // --- small persistent buffers ---
  unsigned short* Wt_ig  = (unsigned short*)alloc((size_t)1024 * 512 * 2);
  unsigned short* Wt_out = (unsigned short*)alloc((size_t)512 * 512 * 2);
  unsigned short* Wt_ff1 = (unsigned short*)alloc((size_t)1024 * 512 * 2);
  unsigned short* Wt_ff2 = (unsigned short*)alloc((size_t)512 * 1024 * 2);
  float* fa = (float*)alloc((size_t)NCHUNK * CDIM * 4);
  float* ba = (float*)alloc((size_t)NCHUNK * CDIM * 4);
  float* fc = (float*)alloc((size_t)NCHUNK * CDIM * 4);
  float* bc = (float*)alloc((size_t)NCHUNK * CDIM * 4);
  float* gaF = (float*)alloc((size_t)NGRP * CDIM * 4);
  float* gaB = (float*)alloc((size_t)NGRP * CDIM * 4);
  float* GFb = (float*)alloc((size_t)NGRP * CDIM * 4);
  float* GBb = (float*)alloc((size_t)NGRP * CDIM * 4);
  float* decay  = (float*)alloc(CDIM * 4);
  float* decayT = (float*)alloc(CDIM * 4);
  // --- large aliased regions (liveness-disjoint) ---
  const size_t LC2 = (size_t)L_SEQ * CDIM * 2; // 33.55 MB
  unsigned short* R1 = (unsigned short*)alloc(LC2);      // hidden -> state -> hbuf
  unsigned short* R2 = (unsigned short*)alloc(LC2);      // u(bf16) -> ffb[0:]
  unsigned short* R3 = (unsigned short*)alloc(LC2);      // gate    -> ffb[L*C:]
  unsigned short* hidden = R1;
  unsigned short* state  = R1;
  unsigned short* hbuf   = R1;
  unsigned short* u_buf  = R2;
  unsigned short* gate   = R3;
  unsigned short* ffb    = R2; // 67 MB spanning R2+R3 (contiguous)
  float* x2 = (float*)d_out;   // d_out doubles as x2 buffer

  // single prep launch: all transposes + decay
  prep_all<<<1793, 256, 0, stream>>>(W_in, W_gate, W_out, W_ff1, W_ff2,
      decay_logit, Wt_ig, Wt_out, Wt_ff1, Wt_ff2, decay, decayT);

  // LN1
  ln_kernel<<<L_SEQ / 4, 256, 0, stream>>>(x, ln1_w, ln1_b, hidden);

  // u | gate fused GEMM (N=1024); grid = (M/128, N/128)
  gemm_bt<0><<<dim3(L_SEQ / 128, 1024 / 128), 256, 0, stream>>>(
      hidden, Wt_ig, b_in, b_gate, nullptr, nullptr, u_buf, gate, L_SEQ, 1024, 512);

  // bidirectional scan (hierarchical)
  scan_phase1<<<NCHUNK, 512, 0, stream>>>(u_buf, decay, fa, ba);
  scan_p2a<<<NGRP, 512, 0, stream>>>(fa, ba, decayT, fc, bc, gaF, gaB);
  scan_p2b<<<1, 512, 0, stream>>>(gaF, gaB, decayT, GFb, GBb);
  scan_phase3<<<NCHUNK, 512, 0, stream>>>(u_buf, gate, decay, decayT, fc, bc,
      GFb, GBb, state);

  // x2 = x + state @ W_out + b_out   (written to d_out)
  gemm_bt<1><<<dim3(L_SEQ / 128, 512 / 128), 256, 0, stream>>>(
      state, Wt_out, b_out, nullptr, x, x2, nullptr, nullptr, L_SEQ, 512, 512);

  // LN2
  ln_kernel<<<L_SEQ / 4, 256, 0, stream>>>(x2, ln2_w, ln2_b, hbuf);

  // ff = silu(h @ W_ff1 + b_ff1)
  gemm_bt<2><<<dim3(L_SEQ / 128, 1024 / 128), 256, 0, stream>>>(
      hbuf, Wt_ff1, b_ff1, nullptr, nullptr, nullptr, nullptr, ffb, L_SEQ, 1024, 512);

  // out = x2 + ff @ W_ff2 + b_ff2   (in-place read/write on d_out is per-element safe)
  gemm_bt<1><<<dim3(L_SEQ / 128, 512 / 128), 256, 0, stream>>>(
      ffb, Wt_ff2, b_ff2, nullptr, x2, x2, nullptr, nullptr, L_SEQ, 512, 1024);
}

// Round 7
// 414.817 us; speedup vs baseline: 1.1313x; 1.0399x over previous
//
#include <hip/hip_runtime.h>
#include <stdint.h>

// ---------------------------------------------------------------------------
// MambaLikeBlock on MI355X (gfx950)
// R13: GEMM K-loop: 2-buffer full-drain -> 3-slot ring with counted vmcnt.
//     R11/R12's loop drains vmcnt(0) (+ __syncthreads' own implicit full
//     drain) every iteration -> each staged tile gets only ~500cyc of
//     flight vs ~900cyc memory latency -> ~serial stall per iter (the
//     invariant ~6000cyc/block-iter seen across R8-R12). Ring-3 stages
//     tile k+2 at iter k and waits vmcnt(4) at iter end (tile k+1 done,
//     newest stage stays in flight across the RAW s_barrier) -> ~1.7
//     iters of flight. LDS 48KB -> 3 blocks/CU (co-residency kept).
//     WAR: slot (j+2)%3 == slot (j-1)%3, whose reads completed before the
//     end-of-iter-(j-1) barrier (all ds_reads consumed by MFMAs).
//     Scans/LN/prep unchanged from R12 (431us, scan fix verified).
// ---------------------------------------------------------------------------

#define L_SEQ 32768
#define CDIM 512
#define LN_EPS 1e-5f
#define CHUNK 64
#define NCHUNK (L_SEQ / CHUNK) // 512
#define NGRP 16
#define GCHUNK (NCHUNK / NGRP) // 32

typedef __attribute__((ext_vector_type(8))) short short8;
typedef __attribute__((ext_vector_type(4))) float floatx4;

__device__ inline unsigned short f2bf(float f) {
  union { float f; unsigned int u; } v; v.f = f;
  unsigned int r = v.u + 0x7fffu + ((v.u >> 16) & 1u);
  return (unsigned short)(r >> 16);
}
__device__ inline float bf2f(unsigned short h) {
  union { float f; unsigned int u; } v; v.u = ((unsigned int)h) << 16;
  return v.f;
}
__device__ inline float sigmoidf_(float x) { return 1.0f / (1.0f + __expf(-x)); }

// dT^e for e in [0,31], 5 square-and-multiply steps
__device__ inline float powi5(float s, int e) {
  float p = 1.f;
#pragma unroll
  for (int b = 0; b < 5; b++) { if (e & (1 << b)) p *= s; s *= s; }
  return p;
}

// global -> LDS direct copy, 16B per lane.
__device__ __forceinline__ void gll16(const void* g, void* l) {
  __builtin_amdgcn_global_load_lds(
      (__attribute__((address_space(1))) void*)g,
      (__attribute__((address_space(3))) void*)l, 16, 0, 0);
}

// ---------------- LayerNorm: one wave per row (C=512 = 64 lanes x 8) -------
__global__ __launch_bounds__(256) void ln_kernel(const float* __restrict__ x,
    const float* __restrict__ w, const float* __restrict__ b,
    unsigned short* __restrict__ out) {
  int row = blockIdx.x * 4 + (threadIdx.x >> 6);
  int lane = threadIdx.x & 63;
  const float4* xr = (const float4*)(x + (size_t)row * CDIM);
  float4 v0 = xr[lane * 2];
  float4 v1 = xr[lane * 2 + 1];
  float s = v0.x + v0.y + v0.z + v0.w + v1.x + v1.y + v1.z + v1.w;
  float s2 = v0.x * v0.x + v0.y * v0.y + v0.z * v0.z + v0.w * v0.w +
             v1.x * v1.x + v1.y * v1.y + v1.z * v1.z + v1.w * v1.w;
  for (int m = 32; m > 0; m >>= 1) {
    s += __shfl_xor(s, m, 64);
    s2 += __shfl_xor(s2, m, 64);
  }
  float mean = s * (1.0f / CDIM);
  float var = s2 * (1.0f / CDIM) - mean * mean;
  float rs = rsqrtf(var + LN_EPS);
  const float4* wr = (const float4*)w;
  const float4* br = (const float4*)b;
  float4 w0 = wr[lane * 2], w1 = wr[lane * 2 + 1];
  float4 b0 = br[lane * 2], b1 = br[lane * 2 + 1];
  unsigned int p0 = (unsigned int)f2bf((v0.x - mean) * rs * w0.x + b0.x) |
                    ((unsigned int)f2bf((v0.y - mean) * rs * w0.y + b0.y) << 16);
  unsigned int p1 = (unsigned int)f2bf((v0.z - mean) * rs * w0.z + b0.z) |
                    ((unsigned int)f2bf((v0.w - mean) * rs * w0.w + b0.w) << 16);
  unsigned int p2 = (unsigned int)f2bf((v1.x - mean) * rs * w1.x + b1.x) |
                    ((unsigned int)f2bf((v1.y - mean) * rs * w1.y + b1.y) << 16);
  unsigned int p3 = (unsigned int)f2bf((v1.z - mean) * rs * w1.z + b1.z) |
                    ((unsigned int)f2bf((v1.w - mean) * rs * w1.w + b1.w) << 16);
  uint4 pk; pk.x = p0; pk.y = p1; pk.z = p2; pk.w = p3;
  *((uint4*)(out + (size_t)row * CDIM + lane * 8)) = pk;
}

// ---------------- Combined prep: 5 weight transposes + decay (1 launch) ----
__global__ __launch_bounds__(256) void prep_all(
    const float* __restrict__ W_in, const float* __restrict__ W_gate,
    const float* __restrict__ W_out, const float* __restrict__ W_ff1,
    const float* __restrict__ W_ff2, const float* __restrict__ logit,
    unsigned short* __restrict__ Wt_ig, unsigned short* __restrict__ Wt_out,
    unsigned short* __restrict__ Wt_ff1, unsigned short* __restrict__ Wt_ff2,
    float* __restrict__ decay, float* __restrict__ decayT) {
  int b = blockIdx.x;
  if (b >= 1792) { // decay prep
    for (int c = threadIdx.x; c < CDIM; c += 256) {
      float d = sigmoidf_(logit[c]);
      decay[c] = d;
      float p = d;
      for (int i = 0; i < 6; i++) p *= p; // d^64
      decayT[c] = p;
    }
    return;
  }
  const float* W; unsigned short* Wt; int Kd, Nd, t;
  if (b < 256)       { W = W_in;   Wt = Wt_ig;             Kd = 512;  Nd = 512;  t = b; }
  else if (b < 512)  { W = W_gate; Wt = Wt_ig + 512 * 512; Kd = 512;  Nd = 512;  t = b - 256; }
  else if (b < 768)  { W = W_out;  Wt = Wt_out;            Kd = 512;  Nd = 512;  t = b - 512; }
  else if (b < 1280) { W = W_ff1;  Wt = Wt_ff1;            Kd = 512;  Nd = 1024; t = b - 768; }
  else               { W = W_ff2;  Wt = Wt_ff2;            Kd = 1024; Nd = 512;  t = b - 1280; }
  int ntx = Nd >> 5;
  int n0 = (t % ntx) * 32, k0 = (t / ntx) * 32;
  __shared__ float tile[32][33];
  int tx = threadIdx.x & 31, ty = threadIdx.x >> 5; // 32x8
  for (int r = 0; r < 32; r += 8)
    tile[ty + r][tx] = W[(size_t)(k0 + ty + r) * Nd + n0 + tx];
  __syncthreads();
  for (int r = 0; r < 32; r += 8)
    Wt[(size_t)(n0 + ty + r) * Kd + k0 + tx] = f2bf(tile[tx][ty + r]);
}

// ---------------- bf16 MFMA GEMM: C = A(MxK) * Bt(NxK)^T + epilogue --------
// 128x128 tile, 256 threads = 4 waves (2x2), per-wave 64x64 out (4x4 frags).
// BK=32. LDS: 3-slot ring (3 x 16KB = 48KB, epilogue aliases first 34KB)
// -> 3 blocks/CU. K-loop: stage tile k+2; counted vmcnt(4) + RAW s_barrier
// per iter (tile k+1 guaranteed, newest stage in flight across barrier).
template <int EPI>
__global__ __launch_bounds__(256, 3) void gemm_bt(
    const unsigned short* __restrict__ A, const unsigned short* __restrict__ Bt,
    const float* __restrict__ biasA, const float* __restrict__ biasB,
    const float* __restrict__ res, float* __restrict__ outF,
    unsigned short* __restrict__ outU, unsigned short* __restrict__ outG,
    int M, int N, int K) {
  __shared__ char smemRaw[49152];
  unsigned short* As = (unsigned short*)smemRaw;            // 3 slots x 4096 elems
  unsigned short* Bs = (unsigned short*)(smemRaw + 24576);  // 3 slots x 4096 elems

  int nbx = gridDim.x, nby = gridDim.y;
  int bid = blockIdx.x + blockIdx.y * nbx;
  int per = (nbx * nby) >> 3;
  int w = (bid & 7) * per + (bid >> 3);
  int ni = w % nby;
  int mi = w / nby;
  int bm = mi << 7, bn = ni << 7;

  int tid = threadIdx.x, wave = tid >> 6, lane = tid & 63;
  int wm = (wave >> 1) * 64, wn = (wave & 1) * 64;

  // staging addressing (R6-verified swizzled layout; measured 0 conflicts)
  int srow = wave * 16 + (lane >> 2);
  int chunkSel = (lane & 3) ^ ((lane >> 3) & 3);
  int scol = chunkSel * 8;
  const unsigned short* aP0 = A + (size_t)(bm + srow) * K + scol;
  const unsigned short* aP1 = A + (size_t)(bm + 64 + srow) * K + scol;
  const unsigned short* bP0 = Bt + (size_t)(bn + srow) * K + scol;
  const unsigned short* bP1 = Bt + (size_t)(bn + 64 + srow) * K + scol;
  int wbase = wave * 512; // wave-uniform LDS elem offset; HW adds lane*16B

#define STAGE(slotOff, ktile) do {                                \
    int _o = (ktile) * 32;                                        \
    gll16(aP0 + _o, As + (slotOff) + wbase);                      \
    gll16(aP1 + _o, As + (slotOff) + 2048 + wbase);               \
    gll16(bP0 + _o, Bs + (slotOff) + wbase);                      \
    gll16(bP1 + _o, Bs + (slotOff) + 2048 + wbase);               \
  } while (0)

  floatx4 acc[4][4];
#pragma unroll
  for (int i = 0; i < 4; i++)
#pragma unroll
    for (int j = 0; j < 4; j++) acc[i][j] = (floatx4){0.f, 0.f, 0.f, 0.f};

  int quad = lane >> 4, r16 = lane & 15;
  int cSwz = ((quad ^ (r16 >> 1)) & 3) * 8; // inverse of staging swizzle

  int NK = K >> 5;

  // prologue: stage tiles 0,1; wait tile0 (tile1's 4 loads may stay out)
  STAGE(0, 0);
  STAGE(4096, 1);
  asm volatile("s_waitcnt vmcnt(4)" ::: "memory");
  __builtin_amdgcn_s_barrier();
  asm volatile("" ::: "memory");

  int sC = 0; // current slot elem offset /4096
  for (int k = 0; k < NK; ++k) {
    int cur = sC * 4096;
    int sT = sC + 2; if (sT >= 3) sT -= 3;   // slot for tile k+2
    if (k + 2 < NK) STAGE(sT * 4096, k + 2);
    short8 af[4], bfm[4];
#pragma unroll
    for (int i = 0; i < 4; i++)
      af[i] = *(const short8*)(&As[cur + (wm + i * 16 + r16) * 32 + cSwz]);
#pragma unroll
    for (int j = 0; j < 4; j++)
      bfm[j] = *(const short8*)(&Bs[cur + (wn + j * 16 + r16) * 32 + cSwz]);
#pragma unroll
    for (int i = 0; i < 4; i++)
#pragma unroll
      for (int j = 0; j < 4; j++)
        acc[i][j] = __builtin_amdgcn_mfma_f32_16x16x32_bf16(af[i], bfm[j], acc[i][j], 0, 0, 0);
    // counted wait: tile k+1 must be resident; newest stage stays in flight.
    if (k + 2 < NK)      asm volatile("s_waitcnt vmcnt(4)" ::: "memory");
    else if (k + 1 < NK) asm volatile("s_waitcnt vmcnt(0)" ::: "memory");
    __builtin_amdgcn_s_barrier();
    asm volatile("" ::: "memory");
    sC = sC + 1 == 3 ? 0 : sC + 1;
  }
#undef STAGE

  if (EPI == 1) {
    // fp32 output: 16 lanes x 4B = 64B aligned segments, direct stores
#pragma unroll
    for (int j = 0; j < 4; j++) {
      int n = bn + wn + j * 16 + r16;
#pragma unroll
      for (int i = 0; i < 4; i++) {
        int mb = bm + wm + i * 16 + quad * 4;
#pragma unroll
        for (int r = 0; r < 4; r++) {
          size_t idx = (size_t)(mb + r) * N + n;
          outF[idx] = res[idx] + acc[i][j][r] + biasA[n];
        }
      }
    }
  } else {
    // bf16 output: stage tile in LDS, then coalesced 16B/lane stores
    unsigned short* sm = (unsigned short*)smemRaw;
#pragma unroll
    for (int j = 0; j < 4; j++) {
      int n = bn + wn + j * 16 + r16;
      int ln = wn + j * 16 + r16;
#pragma unroll
      for (int i = 0; i < 4; i++) {
        int lmb = wm + i * 16 + quad * 4;
#pragma unroll
        for (int r = 0; r < 4; r++) {
          float v = acc[i][j][r];
          float t;
          if (EPI == 0) {
            t = (n < 512) ? (v + biasA[n]) : sigmoidf_(v + biasB[n - 512]);
          } else { // EPI == 2
            float z = v + biasA[n];
            t = z * sigmoidf_(z);
          }
          sm[(lmb + r) * 132 + ln] = f2bf(t);
        }
      }
    }
    __syncthreads();
    int row = tid >> 1, half = tid & 1;
    const unsigned short* src = sm + row * 132 + half * 64;
    unsigned short* gptr;
    if (EPI == 0) {
      gptr = ((bn < 512) ? outU : (outG - 512)) + (size_t)(bm + row) * 512 + bn + half * 64;
    } else {
      gptr = outG + (size_t)(bm + row) * N + bn + half * 64;
    }
#pragma unroll
    for (int s = 0; s < 8; s++)
      *(short8*)(gptr + s * 8) = *(const short8*)(src + s * 8);
  }
}

// ---------------- Scan phase 1: per-chunk fwd/bwd aggregates ---------------
__global__ __launch_bounds__(512) void scan_phase1(const unsigned short* __restrict__ u,
    const float* __restrict__ decay, float* __restrict__ fa, float* __restrict__ ba) {
  int c = threadIdx.x, k = blockIdx.x;
  float d = decay[c];
  const unsigned short* up = u + (size_t)k * CHUNK * CDIM + c;
  float f = 0.f, bs = 0.f, p = 1.f;
#pragma unroll 8
  for (int t = 0; t < CHUNK; t++) {
    float v = bf2f(up[(size_t)t * CDIM]);
    f = d * f + v;
    bs += p * v;
    p *= d;
  }
  fa[(size_t)k * CDIM + c] = f;
  ba[(size_t)k * CDIM + c] = bs;
}

// ---------------- Scan phase 2a: group-local carries + group aggregates ----
__global__ __launch_bounds__(512) void scan_p2a(const float* __restrict__ fa,
    const float* __restrict__ ba, const float* __restrict__ decayT,
    float* __restrict__ fc, float* __restrict__ bc,
    float* __restrict__ gaF, float* __restrict__ gaB) {
  int c = threadIdx.x, g = blockIdx.x;
  float dT = decayT[c];
  int k0 = g * GCHUNK;
  float runf = 0.f;
#pragma unroll 4
  for (int j = 0; j < GCHUNK; j++) {
    size_t idx = (size_t)(k0 + j) * CDIM + c;
    fc[idx] = runf;
    runf = dT * runf + fa[idx];
  }
  gaF[(size_t)g * CDIM + c] = runf;
  float runb = 0.f;
#pragma unroll 4
  for (int j = GCHUNK - 1; j >= 0; j--) {
    size_t idx = (size_t)(k0 + j) * CDIM + c;
    bc[idx] = runb;
    runb = dT * runb + ba[idx];
  }
  gaB[(size_t)g * CDIM + c] = runb;
}

// ---------------- Scan phase 2b: 16-step group recurrence ------------------
__global__ __launch_bounds__(512) void scan_p2b(const float* __restrict__ gaF,
    const float* __restrict__ gaB, const float* __restrict__ decayT,
    float* __restrict__ GF, float* __restrict__ GB) {
  int c = threadIdx.x;
  float dT = decayT[c];
  float d32 = dT;
#pragma unroll
  for (int i = 0; i < 5; i++) d32 *= d32;  // dT^32
  float gf = 0.f;
#pragma unroll
  for (int g = 0; g < NGRP; g++) {
    GF[(size_t)g * CDIM + c] = gf;
    gf = d32 * gf + gaF[(size_t)g * CDIM + c];
  }
  float gb = 0.f;
#pragma unroll
  for (int g = NGRP - 1; g >= 0; g--) {
    GB[(size_t)g * CDIM + c] = gb;
    gb = d32 * gb + gaB[(size_t)g * CDIM + c];
  }
}

// ---------------- Scan phase 3: apply carries, combine, gate ---------------
__global__ __launch_bounds__(512) void scan_phase3(const unsigned short* __restrict__ u,
    const unsigned short* __restrict__ gate, const float* __restrict__ decay,
    const float* __restrict__ decayT, const float* __restrict__ fc,
    const float* __restrict__ bc, const float* __restrict__ GF,
    const float* __restrict__ GB, unsigned short* __restrict__ state) {
  int c = threadIdx.x, k = blockIdx.x;
  int g = k >> 5, j = k & 31;
  float d = decay[c];
  float dT = decayT[c];
  size_t base = (size_t)k * CHUNK * CDIM + c;
  size_t kc = (size_t)k * CDIM + c;
  size_t gc = (size_t)g * CDIM + c;
  float run  = fc[kc] + powi5(dT, j) * GF[gc];
  float runb0 = bc[kc] + powi5(dT, 31 - j) * GB[gc];
  float fwd[CHUNK];
  unsigned int us[CHUNK / 2];
#pragma unroll
  for (int t = 0; t < CHUNK; t++) {
    unsigned short uv = u[base + (size_t)t * CDIM];
    if (t & 1) us[t >> 1] |= ((unsigned int)uv) << 16;
    else       us[t >> 1] = uv;
    run = d * run + bf2f(uv);
    fwd[t] = run;
  }
  float runb = runb0;
#pragma unroll
  for (int t = CHUNK - 1; t >= 0; t--) {
    unsigned short uv = (unsigned short)((us[t >> 1] >> ((t & 1) * 16)) & 0xffffu);
    runb = d * runb + bf2f(uv);
    float gv = bf2f(gate[base + (size_t)t * CDIM]);
    state[base + (size_t)t * CDIM] = f2bf(0.5f * (fwd[t] + runb) * gv);
  }
}

// ---------------------------------------------------------------------------
extern "C" void kernel_launch(void* const* d_in, const int* in_sizes, int n_in,
                              void* d_out, int out_size, void* d_ws, size_t ws_size,
                              hipStream_t stream) {
  const float* x = (const float*)d_in[0];
  const float* ln1_w = (const float*)d_in[1];
  const float* ln1_b = (const float*)d_in[2];
  const float* W_in = (const float*)d_in[3];
  const float* b_in = (const float*)d_in[4];
  const float* W_gate = (const float*)d_in[5];
  const float* b_gate = (const float*)d_in[6];
  const float* W_out = (const float*)d_in[7];
  const float* b_out = (const float*)d_in[8];
  const float* decay_logit = (const float*)d_in[9];
  const float* ln2_w = (const float*)d_in[10];
  const float* ln2_b = (const float*)d_in[11];
  const float* W_ff1 = (const float*)d_in[12];
  const float* b_ff1 = (const float*)d_in[13];
  const float* W_ff2 = (const float*)d_in[14];
  const float* b_ff2 = (const float*)d_in[15];

  char* ws = (char*)d_ws;
  size_t off = 0;
  auto alloc = [&](size_t bytes) -> void* {
    void* p = ws + off;
    off += (bytes + 255) & ~(size_t)255;
    return p;
  };
  // --- small persistent buffers ---
  unsigned short* Wt_ig  = (unsigned short*)alloc((size_t)1024 * 512 * 2);
  unsigned short* Wt_out = (unsigned short*)alloc((size_t)512 * 512 * 2);
  unsigned short* Wt_ff1 = (unsigned short*)alloc((size_t)1024 * 512 * 2);
  unsigned short* Wt_ff2 = (unsigned short*)alloc((size_t)512 * 1024 * 2);
  float* fa = (float*)alloc((size_t)NCHUNK * CDIM * 4);
  float* ba = (float*)alloc((size_t)NCHUNK * CDIM * 4);
  float* fc = (float*)alloc((size_t)NCHUNK * CDIM * 4);
  float* bc = (float*)alloc((size_t)NCHUNK * CDIM * 4);
  float* gaF = (float*)alloc((size_t)NGRP * CDIM * 4);
  float* gaB = (float*)alloc((size_t)NGRP * CDIM * 4);
  float* GFb = (float*)alloc((size_t)NGRP * CDIM * 4);
  float* GBb = (float*)alloc((size_t)NGRP * CDIM * 4);
  float* decay  = (float*)alloc(CDIM * 4);
  float* decayT = (float*)alloc(CDIM * 4);
  // --- large aliased regions (liveness-disjoint) ---
  const size_t LC2 = (size_t)L_SEQ * CDIM * 2; // 33.55 MB
  unsigned short* R1 = (unsigned short*)alloc(LC2);      // hidden -> state -> hbuf
  unsigned short* R2 = (unsigned short*)alloc(LC2);      // u(bf16) -> ffb[0:]
  unsigned short* R3 = (unsigned short*)alloc(LC2);      // gate    -> ffb[L*C:]
  unsigned short* hidden = R1;
  unsigned short* state  = R1;
  unsigned short* hbuf   = R1;
  unsigned short* u_buf  = R2;
  unsigned short* gate   = R3;
  unsigned short* ffb    = R2; // 67 MB spanning R2+R3 (contiguous)
  float* x2 = (float*)d_out;   // d_out doubles as x2 buffer

  // single prep launch: all transposes + decay
  prep_all<<<1793, 256, 0, stream>>>(W_in, W_gate, W_out, W_ff1, W_ff2,
      decay_logit, Wt_ig, Wt_out, Wt_ff1, Wt_ff2, decay, decayT);

  // LN1
  ln_kernel<<<L_SEQ / 4, 256, 0, stream>>>(x, ln1_w, ln1_b, hidden);

  // u | gate fused GEMM (N=1024); grid = (M/128, N/128)
  gemm_bt<0><<<dim3(L_SEQ / 128, 1024 / 128), 256, 0, stream>>>(
      hidden, Wt_ig, b_in, b_gate, nullptr, nullptr, u_buf, gate, L_SEQ, 1024, 512);

  // bidirectional scan (hierarchical)
  scan_phase1<<<NCHUNK, 512, 0, stream>>>(u_buf, decay, fa, ba);
  scan_p2a<<<NGRP, 512, 0, stream>>>(fa, ba, decayT, fc, bc, gaF, gaB);
  scan_p2b<<<1, 512, 0, stream>>>(gaF, gaB, decayT, GFb, GBb);
  scan_phase3<<<NCHUNK, 512, 0, stream>>>(u_buf, gate, decay, decayT, fc, bc,
      GFb, GBb, state);

  // x2 = x + state @ W_out + b_out   (written to d_out)
  gemm_bt<1><<<dim3(L_SEQ / 128, 512 / 128), 256, 0, stream>>>(
      state, Wt_out, b_out, nullptr, x, x2, nullptr, nullptr, L_SEQ, 512, 512);

  // LN2
  ln_kernel<<<L_SEQ / 4, 256, 0, stream>>>(x2, ln2_w, ln2_b, hbuf);

  // ff = silu(h @ W_ff1 + b_ff1)
  gemm_bt<2><<<dim3(L_SEQ / 128, 1024 / 128), 256, 0, stream>>>(
      hbuf, Wt_ff1, b_ff1, nullptr, nullptr, nullptr, nullptr, ffb, L_SEQ, 1024, 512);

  // out = x2 + ff @ W_ff2 + b_ff2   (in-place read/write on d_out is per-element safe)
  gemm_bt<1><<<dim3(L_SEQ / 128, 512 / 128), 256, 0, stream>>>(
      ffb, Wt_ff2, b_ff2, nullptr, x2, x2, nullptr, nullptr, L_SEQ, 512, 1024);
}